// Round 1
// baseline (448.042 us; speedup 1.0000x reference)
//
#include <hip/hip_runtime.h>

#define B_ 4
#define N_ 2048
#define C_ 256
#define H_ 4
#define D_ 64

// ---------------- QKV projection: C[m][o] = x[m][:]·w[o][:] + b[o] ----------------
// scatter to q/k/v laid out [three][b][h][n][d] in workspace
__global__ __launch_bounds__(256) void qkv_kernel(
    const float* __restrict__ x, const float* __restrict__ w,
    const float* __restrict__ bias, float* __restrict__ qkv)
{
    __shared__ float Xs[16][68];
    __shared__ float Ws[16][68];
    const int m0 = blockIdx.x * 64;
    const int o0 = blockIdx.y * 64;
    const int tid = threadIdx.x;
    const int tx = tid & 15, ty = tid >> 4;
    const int lrow = tid >> 2;          // 0..63
    const int lkq  = (tid & 3) << 2;    // 0,4,8,12

    float acc[4][4] = {{0.f,0.f,0.f,0.f},{0.f,0.f,0.f,0.f},{0.f,0.f,0.f,0.f},{0.f,0.f,0.f,0.f}};

    for (int k0 = 0; k0 < 256; k0 += 16) {
        float4 xv = *(const float4*)(x + (size_t)(m0 + lrow) * 256 + k0 + lkq);
        float4 wv = *(const float4*)(w + (size_t)(o0 + lrow) * 256 + k0 + lkq);
        Xs[lkq+0][lrow] = xv.x; Xs[lkq+1][lrow] = xv.y; Xs[lkq+2][lrow] = xv.z; Xs[lkq+3][lrow] = xv.w;
        Ws[lkq+0][lrow] = wv.x; Ws[lkq+1][lrow] = wv.y; Ws[lkq+2][lrow] = wv.z; Ws[lkq+3][lrow] = wv.w;
        __syncthreads();
        #pragma unroll
        for (int kk = 0; kk < 16; ++kk) {
            float4 xa = *(const float4*)&Xs[kk][ty << 2];
            float4 wb = *(const float4*)&Ws[kk][tx << 2];
            float xs[4] = {xa.x, xa.y, xa.z, xa.w};
            float wsv[4] = {wb.x, wb.y, wb.z, wb.w};
            #pragma unroll
            for (int i = 0; i < 4; ++i)
                #pragma unroll
                for (int j = 0; j < 4; ++j)
                    acc[i][j] += xs[i] * wsv[j];
        }
        __syncthreads();
    }

    // o0 is a multiple of 64 -> whole block shares (three, h)
    const int three = o0 >> 8;
    const int h = (o0 >> 6) & 3;
    float4 bb = *(const float4*)&bias[o0 + (tx << 2)];
    #pragma unroll
    for (int i = 0; i < 4; ++i) {
        int m = m0 + (ty << 2) + i;
        int b = m >> 11, n = m & 2047;
        float4 val;
        val.x = acc[i][0] + bb.x; val.y = acc[i][1] + bb.y;
        val.z = acc[i][2] + bb.z; val.w = acc[i][3] + bb.w;
        size_t idx = ((((size_t)three * B_ + b) * H_ + h) * N_ + n) * D_ + (tx << 2);
        *(float4*)&qkv[idx] = val;
    }
}

// ---------------- Flash attention with Lie positional bias ----------------
// block: (b,h) x 64-query tile; online softmax; bias_ij = ps * (R@P_i)·P_j
__global__ __launch_bounds__(256) void attn_kernel(
    const float* __restrict__ qkv, const float* __restrict__ Rm,
    const float* __restrict__ Pm, const float* __restrict__ ps_ptr,
    float* __restrict__ obuf)
{
    __shared__ float Qs[64][68];
    __shared__ float KP[64][68];   // holds K^T [d][key] during S, then P [query][key]
    __shared__ float Vs[64][68];   // [key][d]
    __shared__ float rp[64][3];
    __shared__ float pj[64][3];
    __shared__ float mrow[64], lrow[64], arow[64];

    const int bh = blockIdx.y;
    const int b = bh >> 2, h = bh & 3;
    const int i0 = blockIdx.x * 64;
    const int tid = threadIdx.x;
    const int tx = tid & 15, ty = tid >> 4;
    const float scale = 0.125f;          // D^-0.5 = 64^-0.5
    const float ps = ps_ptr[0];

    const size_t stride_bh = (size_t)B_ * H_ * N_ * D_;
    const size_t base = (((size_t)b * H_) + h) * N_ * D_;
    const float* q = qkv + base;
    const float* k = qkv + stride_bh + base;
    const float* v = qkv + 2 * stride_bh + base;

    // stage Q tile [query][d]
    #pragma unroll
    for (int r = 0; r < 4; ++r) {
        int idx = tid + (r << 8);
        int row = idx >> 4, c = (idx & 15) << 2;
        *(float4*)&Qs[row][c] = *(const float4*)&q[(size_t)(i0 + row) * D_ + c];
    }
    if (tid < 64) {
        float p0 = Pm[(i0 + tid) * 3 + 0];
        float p1 = Pm[(i0 + tid) * 3 + 1];
        float p2 = Pm[(i0 + tid) * 3 + 2];
        #pragma unroll
        for (int c = 0; c < 3; ++c)
            rp[tid][c] = Rm[b * 9 + c * 3 + 0] * p0 + Rm[b * 9 + c * 3 + 1] * p1
                       + Rm[b * 9 + c * 3 + 2] * p2;
        mrow[tid] = -1e30f;
        lrow[tid] = 0.f;
    }

    float o_acc[4][4] = {{0.f,0.f,0.f,0.f},{0.f,0.f,0.f,0.f},{0.f,0.f,0.f,0.f},{0.f,0.f,0.f,0.f}};

    for (int j0 = 0; j0 < N_; j0 += 64) {
        __syncthreads();  // A: prev-iter PV done reading KP/Vs/arow
        // stage K^T [d][key], V [key][d], P_j
        #pragma unroll
        for (int r = 0; r < 4; ++r) {
            int idx = tid + (r << 8);
            int row = idx >> 4, c = (idx & 15) << 2;
            float4 kv = *(const float4*)&k[(size_t)(j0 + row) * D_ + c];
            KP[c+0][row] = kv.x; KP[c+1][row] = kv.y; KP[c+2][row] = kv.z; KP[c+3][row] = kv.w;
            *(float4*)&Vs[row][c] = *(const float4*)&v[(size_t)(j0 + row) * D_ + c];
        }
        if (tid < 64) {
            pj[tid][0] = Pm[(j0 + tid) * 3 + 0];
            pj[tid][1] = Pm[(j0 + tid) * 3 + 1];
            pj[tid][2] = Pm[(j0 + tid) * 3 + 2];
        }
        __syncthreads();  // B

        // S = Q K^T  (4 queries x 4 keys per thread)
        float s[4][4] = {{0.f,0.f,0.f,0.f},{0.f,0.f,0.f,0.f},{0.f,0.f,0.f,0.f},{0.f,0.f,0.f,0.f}};
        #pragma unroll 4
        for (int d0 = 0; d0 < 64; d0 += 4) {
            float4 q4[4], k4[4];
            #pragma unroll
            for (int i = 0; i < 4; ++i) q4[i] = *(const float4*)&Qs[(ty << 2) + i][d0];
            #pragma unroll
            for (int dd = 0; dd < 4; ++dd) k4[dd] = *(const float4*)&KP[d0 + dd][tx << 2];
            #pragma unroll
            for (int i = 0; i < 4; ++i) {
                float qv[4] = {q4[i].x, q4[i].y, q4[i].z, q4[i].w};
                #pragma unroll
                for (int dd = 0; dd < 4; ++dd) {
                    float kj[4] = {k4[dd].x, k4[dd].y, k4[dd].z, k4[dd].w};
                    #pragma unroll
                    for (int j = 0; j < 4; ++j)
                        s[i][j] += qv[dd] * kj[j];
                }
            }
        }
        __syncthreads();  // C: everyone done reading K^T before overlaying P

        // logits = s*scale + ps*(rp_i · P_j)  -> write into KP as [query][key]
        #pragma unroll
        for (int i = 0; i < 4; ++i) {
            int qi = (ty << 2) + i;
            float r0 = rp[qi][0], r1 = rp[qi][1], r2 = rp[qi][2];
            #pragma unroll
            for (int j = 0; j < 4; ++j) {
                int kj = (tx << 2) + j;
                float bbv = r0 * pj[kj][0] + r1 * pj[kj][1] + r2 * pj[kj][2];
                KP[qi][kj] = s[i][j] * scale + ps * bbv;
            }
        }
        __syncthreads();  // D

        // online softmax: one thread per query row
        if (tid < 64) {
            float mold = mrow[tid];
            float mx = mold;
            #pragma unroll 4
            for (int c4 = 0; c4 < 64; c4 += 4) {
                float4 t = *(const float4*)&KP[tid][c4];
                mx = fmaxf(mx, fmaxf(fmaxf(t.x, t.y), fmaxf(t.z, t.w)));
            }
            float alpha = __expf(mold - mx);
            float sum = 0.f;
            #pragma unroll 4
            for (int c4 = 0; c4 < 64; c4 += 4) {
                float4 t = *(const float4*)&KP[tid][c4];
                t.x = __expf(t.x - mx); t.y = __expf(t.y - mx);
                t.z = __expf(t.z - mx); t.w = __expf(t.w - mx);
                *(float4*)&KP[tid][c4] = t;
                sum += t.x + t.y + t.z + t.w;
            }
            mrow[tid] = mx;
            lrow[tid] = lrow[tid] * alpha + sum;
            arow[tid] = alpha;
        }
        __syncthreads();  // E

        // O = O*alpha + P V
        #pragma unroll
        for (int i = 0; i < 4; ++i) {
            float a = arow[(ty << 2) + i];
            #pragma unroll
            for (int j = 0; j < 4; ++j) o_acc[i][j] *= a;
        }
        #pragma unroll 4
        for (int k0 = 0; k0 < 64; k0 += 4) {
            float4 p4[4], v4[4];
            #pragma unroll
            for (int i = 0; i < 4; ++i) p4[i] = *(const float4*)&KP[(ty << 2) + i][k0];
            #pragma unroll
            for (int dd = 0; dd < 4; ++dd) v4[dd] = *(const float4*)&Vs[k0 + dd][tx << 2];
            #pragma unroll
            for (int i = 0; i < 4; ++i) {
                float pv[4] = {p4[i].x, p4[i].y, p4[i].z, p4[i].w};
                #pragma unroll
                for (int dd = 0; dd < 4; ++dd) {
                    float vj[4] = {v4[dd].x, v4[dd].y, v4[dd].z, v4[dd].w};
                    #pragma unroll
                    for (int j = 0; j < 4; ++j)
                        o_acc[i][j] += pv[dd] * vj[j];
                }
            }
        }
    }

    // epilogue: normalize by l and store [b][h][n][d]
    #pragma unroll
    for (int i = 0; i < 4; ++i) {
        int qi = (ty << 2) + i;
        float inv = 1.f / lrow[qi];
        float4 outv;
        outv.x = o_acc[i][0] * inv; outv.y = o_acc[i][1] * inv;
        outv.z = o_acc[i][2] * inv; outv.w = o_acc[i][3] * inv;
        *(float4*)&obuf[base + (size_t)(i0 + qi) * D_ + (tx << 2)] = outv;
    }
}

// ---------------- Output projection: out[m][o] = oin[m][:]·w[o][:] + b[o] ----------------
// A read gathers [b][h][n][d] -> (B,N,C) logical row-major
__global__ __launch_bounds__(256) void proj_kernel(
    const float* __restrict__ oin, const float* __restrict__ w,
    const float* __restrict__ bias, float* __restrict__ out)
{
    __shared__ float Xs[16][68];
    __shared__ float Ws[16][68];
    const int m0 = blockIdx.x * 64;
    const int o0 = blockIdx.y * 64;
    const int tid = threadIdx.x;
    const int tx = tid & 15, ty = tid >> 4;
    const int lrow = tid >> 2;
    const int lkq  = (tid & 3) << 2;

    float acc[4][4] = {{0.f,0.f,0.f,0.f},{0.f,0.f,0.f,0.f},{0.f,0.f,0.f,0.f},{0.f,0.f,0.f,0.f}};

    const int m = m0 + lrow;
    const int b = m >> 11, n = m & 2047;

    for (int k0 = 0; k0 < 256; k0 += 16) {
        const int hh = k0 >> 6;
        const int dbase = (k0 & 63) + lkq;   // BK=16 never crosses a head boundary
        float4 xv = *(const float4*)&oin[(((size_t)b * H_ + hh) * N_ + n) * D_ + dbase];
        float4 wv = *(const float4*)&w[(size_t)(o0 + lrow) * 256 + k0 + lkq];
        Xs[lkq+0][lrow] = xv.x; Xs[lkq+1][lrow] = xv.y; Xs[lkq+2][lrow] = xv.z; Xs[lkq+3][lrow] = xv.w;
        Ws[lkq+0][lrow] = wv.x; Ws[lkq+1][lrow] = wv.y; Ws[lkq+2][lrow] = wv.z; Ws[lkq+3][lrow] = wv.w;
        __syncthreads();
        #pragma unroll
        for (int kk = 0; kk < 16; ++kk) {
            float4 xa = *(const float4*)&Xs[kk][ty << 2];
            float4 wb = *(const float4*)&Ws[kk][tx << 2];
            float xs[4] = {xa.x, xa.y, xa.z, xa.w};
            float wsv[4] = {wb.x, wb.y, wb.z, wb.w};
            #pragma unroll
            for (int i = 0; i < 4; ++i)
                #pragma unroll
                for (int j = 0; j < 4; ++j)
                    acc[i][j] += xs[i] * wsv[j];
        }
        __syncthreads();
    }

    float4 bb = *(const float4*)&bias[o0 + (tx << 2)];
    #pragma unroll
    for (int i = 0; i < 4; ++i) {
        int mm = m0 + (ty << 2) + i;
        float4 val;
        val.x = acc[i][0] + bb.x; val.y = acc[i][1] + bb.y;
        val.z = acc[i][2] + bb.z; val.w = acc[i][3] + bb.w;
        *(float4*)&out[(size_t)mm * 256 + o0 + (tx << 2)] = val;
    }
}

extern "C" void kernel_launch(void* const* d_in, const int* in_sizes, int n_in,
                              void* d_out, int out_size, void* d_ws, size_t ws_size,
                              hipStream_t stream) {
    const float* x       = (const float*)d_in[0];
    const float* Rm      = (const float*)d_in[1];
    const float* Pm      = (const float*)d_in[2];
    const float* qkv_w   = (const float*)d_in[3];
    const float* qkv_b   = (const float*)d_in[4];
    const float* proj_w  = (const float*)d_in[5];
    const float* proj_b  = (const float*)d_in[6];
    const float* pos_scl = (const float*)d_in[7];
    float* out = (float*)d_out;

    float* qkv  = (float*)d_ws;                                   // 3*B*H*N*D f32 = 24 MB
    float* obuf = qkv + (size_t)3 * B_ * H_ * N_ * D_;            // B*H*N*D f32 = 8 MB

    qkv_kernel<<<dim3(128, 12), 256, 0, stream>>>(x, qkv_w, qkv_b, qkv);
    attn_kernel<<<dim3(32, 16), 256, 0, stream>>>(qkv, Rm, Pm, pos_scl, obuf);
    proj_kernel<<<dim3(128, 4), 256, 0, stream>>>(obuf, proj_w, proj_b, out);
}

// Round 2
// 274.413 us; speedup vs baseline: 1.6327x; 1.6327x over previous
//
#include <hip/hip_runtime.h>

#define B_ 4
#define N_ 2048
#define C_ 256
#define H_ 4
#define D_ 64

typedef __attribute__((ext_vector_type(8))) short bf16x8;
typedef __attribute__((ext_vector_type(4))) float f32x4;

// f32 -> bf16 round-to-nearest-even
static __device__ inline short f2bf(float f) {
    unsigned u = __builtin_bit_cast(unsigned, f);
    unsigned r = (u + 0x7fffu + ((u >> 16) & 1u)) >> 16;
    return (short)r;
}

// ---------------- QKV projection: C[m][o] = x[m][:]·w[o][:] + b[o] ----------------
// scatter to q/k/v laid out [three][b][h][n][d] in workspace
__global__ __launch_bounds__(256) void qkv_kernel(
    const float* __restrict__ x, const float* __restrict__ w,
    const float* __restrict__ bias, float* __restrict__ qkv)
{
    __shared__ float Xs[16][68];
    __shared__ float Ws[16][68];
    const int m0 = blockIdx.x * 64;
    const int o0 = blockIdx.y * 64;
    const int tid = threadIdx.x;
    const int tx = tid & 15, ty = tid >> 4;
    const int lrow = tid >> 2;          // 0..63
    const int lkq  = (tid & 3) << 2;    // 0,4,8,12

    float acc[4][4] = {{0.f,0.f,0.f,0.f},{0.f,0.f,0.f,0.f},{0.f,0.f,0.f,0.f},{0.f,0.f,0.f,0.f}};

    for (int k0 = 0; k0 < 256; k0 += 16) {
        float4 xv = *(const float4*)(x + (size_t)(m0 + lrow) * 256 + k0 + lkq);
        float4 wv = *(const float4*)(w + (size_t)(o0 + lrow) * 256 + k0 + lkq);
        Xs[lkq+0][lrow] = xv.x; Xs[lkq+1][lrow] = xv.y; Xs[lkq+2][lrow] = xv.z; Xs[lkq+3][lrow] = xv.w;
        Ws[lkq+0][lrow] = wv.x; Ws[lkq+1][lrow] = wv.y; Ws[lkq+2][lrow] = wv.z; Ws[lkq+3][lrow] = wv.w;
        __syncthreads();
        #pragma unroll
        for (int kk = 0; kk < 16; ++kk) {
            float4 xa = *(const float4*)&Xs[kk][ty << 2];
            float4 wb = *(const float4*)&Ws[kk][tx << 2];
            float xs[4] = {xa.x, xa.y, xa.z, xa.w};
            float wsv[4] = {wb.x, wb.y, wb.z, wb.w};
            #pragma unroll
            for (int i = 0; i < 4; ++i)
                #pragma unroll
                for (int j = 0; j < 4; ++j)
                    acc[i][j] += xs[i] * wsv[j];
        }
        __syncthreads();
    }

    const int three = o0 >> 8;
    const int h = (o0 >> 6) & 3;
    float4 bb = *(const float4*)&bias[o0 + (tx << 2)];
    #pragma unroll
    for (int i = 0; i < 4; ++i) {
        int m = m0 + (ty << 2) + i;
        int b = m >> 11, n = m & 2047;
        float4 val;
        val.x = acc[i][0] + bb.x; val.y = acc[i][1] + bb.y;
        val.z = acc[i][2] + bb.z; val.w = acc[i][3] + bb.w;
        size_t idx = ((((size_t)three * B_ + b) * H_ + h) * N_ + n) * D_ + (tx << 2);
        *(float4*)&qkv[idx] = val;
    }
}

// ---------------- Flash attention, bf16 MFMA path ----------------
// 64-query tile per block, 4 waves, each wave owns a 16-row strip.
// S = Q K^T via mfma_f32_16x16x32_bf16; bias+softmax f32 in regs; P->LDS->PV.
#define LDK 72   // bf16 elements per LDS row (16B-aligned frags, 2-way banks = free)

__global__ __launch_bounds__(256) void attn_kernel(
    const float* __restrict__ qkv, const float* __restrict__ Rm,
    const float* __restrict__ Pm, const float* __restrict__ ps_ptr,
    float* __restrict__ obuf)
{
    __shared__ __align__(16) short Ks[64 * LDK];  // [key][d]
    __shared__ __align__(16) short Vt[64 * LDK];  // [d][key]
    __shared__ __align__(16) short Ps[64 * LDK];  // [query][key], per-wave 16-row strips

    const int bh = blockIdx.y;
    const int b = bh >> 2, h = bh & 3;
    const int i0 = blockIdx.x * 64;
    const int tid = threadIdx.x;
    const int wave = tid >> 6, lane = tid & 63;
    const int quad = lane >> 4, l16 = lane & 15;
    const float ps = ps_ptr[0];
    const float LOG2E = 1.4426950408889634f;
    const float k_scale = 0.125f * LOG2E;   // D^-0.5 * log2(e), applied to raw QK dot
    const float k_bias  = ps * LOG2E;       // applied to rp·pj

    const size_t sbh = (size_t)B_ * H_ * N_ * D_;
    const size_t base = ((size_t)b * H_ + h) * N_ * D_;
    const float* qg = qkv + base;
    const float* kg = qkv + sbh + base;
    const float* vg = qkv + 2 * sbh + base;

    // Q A-fragments in registers: A[m=l16][k=quad*8+j], rows = i0 + wave*16 + l16
    const int qrow = i0 + wave * 16 + l16;
    bf16x8 aq[2];
    #pragma unroll
    for (int ks = 0; ks < 2; ++ks) {
        const float* p = qg + (size_t)qrow * D_ + ks * 32 + quad * 8;
        #pragma unroll
        for (int j = 0; j < 8; ++j) aq[ks][j] = f2bf(p[j]);
    }

    // rp = R_b @ P_i for this lane's 4 output rows (C-layout rows = quad*4+r)
    float rpr[4][3];
    #pragma unroll
    for (int r = 0; r < 4; ++r) {
        int qi = i0 + wave * 16 + quad * 4 + r;
        float p0 = Pm[qi * 3 + 0], p1 = Pm[qi * 3 + 1], p2 = Pm[qi * 3 + 2];
        #pragma unroll
        for (int c = 0; c < 3; ++c)
            rpr[r][c] = Rm[b * 9 + c * 3 + 0] * p0 + Rm[b * 9 + c * 3 + 1] * p1
                      + Rm[b * 9 + c * 3 + 2] * p2;
    }

    float m_i[4], l_i[4];
    #pragma unroll
    for (int r = 0; r < 4; ++r) { m_i[r] = -1e30f; l_i[r] = 0.f; }
    f32x4 o_acc[4];
    #pragma unroll
    for (int t = 0; t < 4; ++t) o_acc[t] = (f32x4){0.f, 0.f, 0.f, 0.f};

    for (int j0 = 0; j0 < N_; j0 += 64) {
        __syncthreads();  // prev iter's MFMA reads of Ks/Vt done
        // stage K [key][d] and V^T [d][key] as bf16
        #pragma unroll
        for (int rr = 0; rr < 4; ++rr) {
            int idx = tid + (rr << 8);
            int key = idx >> 4, dc = (idx & 15) << 2;
            float4 kv = *(const float4*)&kg[(size_t)(j0 + key) * D_ + dc];
            float4 vv = *(const float4*)&vg[(size_t)(j0 + key) * D_ + dc];
            ushort4 kb;
            kb.x = (unsigned short)f2bf(kv.x); kb.y = (unsigned short)f2bf(kv.y);
            kb.z = (unsigned short)f2bf(kv.z); kb.w = (unsigned short)f2bf(kv.w);
            *(ushort4*)&Ks[key * LDK + dc] = kb;
            Vt[(dc + 0) * LDK + key] = f2bf(vv.x);
            Vt[(dc + 1) * LDK + key] = f2bf(vv.y);
            Vt[(dc + 2) * LDK + key] = f2bf(vv.z);
            Vt[(dc + 3) * LDK + key] = f2bf(vv.w);
        }
        __syncthreads();

        // S strip (16 x 64): 4 col-tiles x 2 k-steps
        f32x4 s[4];
        #pragma unroll
        for (int t = 0; t < 4; ++t) {
            f32x4 c = {0.f, 0.f, 0.f, 0.f};
            #pragma unroll
            for (int ks = 0; ks < 2; ++ks) {
                bf16x8 bk = *(const bf16x8*)&Ks[(l16 + 16 * t) * LDK + ks * 32 + quad * 8];
                c = __builtin_amdgcn_mfma_f32_16x16x32_bf16(aq[ks], bk, c, 0, 0, 0);
            }
            s[t] = c;
        }

        // bias + online softmax (log2 domain); logits row=quad*4+r, col=l16+16t
        float pj[4][3];
        #pragma unroll
        for (int t = 0; t < 4; ++t) {
            int col = j0 + l16 + 16 * t;
            pj[t][0] = Pm[col * 3 + 0]; pj[t][1] = Pm[col * 3 + 1]; pj[t][2] = Pm[col * 3 + 2];
        }
        float lg[4][4], alpha[4];
        #pragma unroll
        for (int r = 0; r < 4; ++r) {
            float mx = m_i[r];
            #pragma unroll
            for (int t = 0; t < 4; ++t) {
                float bias = rpr[r][0] * pj[t][0] + rpr[r][1] * pj[t][1] + rpr[r][2] * pj[t][2];
                float v = s[t][r] * k_scale + bias * k_bias;
                lg[r][t] = v;
                mx = fmaxf(mx, v);
            }
            mx = fmaxf(mx, __shfl_xor(mx, 1));
            mx = fmaxf(mx, __shfl_xor(mx, 2));
            mx = fmaxf(mx, __shfl_xor(mx, 4));
            mx = fmaxf(mx, __shfl_xor(mx, 8));
            alpha[r] = exp2f(m_i[r] - mx);
            float sm = 0.f;
            #pragma unroll
            for (int t = 0; t < 4; ++t) {
                float p = exp2f(lg[r][t] - mx);
                lg[r][t] = p;
                sm += p;
            }
            sm += __shfl_xor(sm, 1);
            sm += __shfl_xor(sm, 2);
            sm += __shfl_xor(sm, 4);
            sm += __shfl_xor(sm, 8);
            m_i[r] = mx;
            l_i[r] = l_i[r] * alpha[r] + sm;
        }

        // P -> this wave's Ps strip (C-layout -> A-layout via LDS; same-wave, no barrier)
        #pragma unroll
        for (int r = 0; r < 4; ++r)
            #pragma unroll
            for (int t = 0; t < 4; ++t)
                Ps[(wave * 16 + quad * 4 + r) * LDK + l16 + 16 * t] = f2bf(lg[r][t]);

        // rescale O
        #pragma unroll
        for (int t = 0; t < 4; ++t)
            #pragma unroll
            for (int r = 0; r < 4; ++r)
                o_acc[t][r] *= alpha[r];

        // O += P V : A = P[m=query][k=key], B = V^T read as B[k=key][n=d]
        #pragma unroll
        for (int ks = 0; ks < 2; ++ks) {
            bf16x8 ap = *(const bf16x8*)&Ps[(wave * 16 + l16) * LDK + ks * 32 + quad * 8];
            #pragma unroll
            for (int t = 0; t < 4; ++t) {
                bf16x8 bv = *(const bf16x8*)&Vt[(l16 + 16 * t) * LDK + ks * 32 + quad * 8];
                o_acc[t] = __builtin_amdgcn_mfma_f32_16x16x32_bf16(ap, bv, o_acc[t], 0, 0, 0);
            }
        }
    }

    // epilogue: normalize by l, store f32 [b][h][n][d]
    #pragma unroll
    for (int r = 0; r < 4; ++r) {
        float inv = 1.f / l_i[r];
        int row = i0 + wave * 16 + quad * 4 + r;
        #pragma unroll
        for (int t = 0; t < 4; ++t)
            obuf[base + (size_t)row * D_ + l16 + 16 * t] = o_acc[t][r] * inv;
    }
}

// ---------------- Output projection: out[m][o] = oin[m][:]·w[o][:] + b[o] ----------------
__global__ __launch_bounds__(256) void proj_kernel(
    const float* __restrict__ oin, const float* __restrict__ w,
    const float* __restrict__ bias, float* __restrict__ out)
{
    __shared__ float Xs[16][68];
    __shared__ float Ws[16][68];
    const int m0 = blockIdx.x * 64;
    const int o0 = blockIdx.y * 64;
    const int tid = threadIdx.x;
    const int tx = tid & 15, ty = tid >> 4;
    const int lrow = tid >> 2;
    const int lkq  = (tid & 3) << 2;

    float acc[4][4] = {{0.f,0.f,0.f,0.f},{0.f,0.f,0.f,0.f},{0.f,0.f,0.f,0.f},{0.f,0.f,0.f,0.f}};

    const int m = m0 + lrow;
    const int b = m >> 11, n = m & 2047;

    for (int k0 = 0; k0 < 256; k0 += 16) {
        const int hh = k0 >> 6;
        const int dbase = (k0 & 63) + lkq;
        float4 xv = *(const float4*)&oin[(((size_t)b * H_ + hh) * N_ + n) * D_ + dbase];
        float4 wv = *(const float4*)&w[(size_t)(o0 + lrow) * 256 + k0 + lkq];
        Xs[lkq+0][lrow] = xv.x; Xs[lkq+1][lrow] = xv.y; Xs[lkq+2][lrow] = xv.z; Xs[lkq+3][lrow] = xv.w;
        Ws[lkq+0][lrow] = wv.x; Ws[lkq+1][lrow] = wv.y; Ws[lkq+2][lrow] = wv.z; Ws[lkq+3][lrow] = wv.w;
        __syncthreads();
        #pragma unroll
        for (int kk = 0; kk < 16; ++kk) {
            float4 xa = *(const float4*)&Xs[kk][ty << 2];
            float4 wb = *(const float4*)&Ws[kk][tx << 2];
            float xs[4] = {xa.x, xa.y, xa.z, xa.w};
            float wsv[4] = {wb.x, wb.y, wb.z, wb.w};
            #pragma unroll
            for (int i = 0; i < 4; ++i)
                #pragma unroll
                for (int j = 0; j < 4; ++j)
                    acc[i][j] += xs[i] * wsv[j];
        }
        __syncthreads();
    }

    float4 bb = *(const float4*)&bias[o0 + (tx << 2)];
    #pragma unroll
    for (int i = 0; i < 4; ++i) {
        int mm = m0 + (ty << 2) + i;
        float4 val;
        val.x = acc[i][0] + bb.x; val.y = acc[i][1] + bb.y;
        val.z = acc[i][2] + bb.z; val.w = acc[i][3] + bb.w;
        *(float4*)&out[(size_t)mm * 256 + o0 + (tx << 2)] = val;
    }
}

extern "C" void kernel_launch(void* const* d_in, const int* in_sizes, int n_in,
                              void* d_out, int out_size, void* d_ws, size_t ws_size,
                              hipStream_t stream) {
    const float* x       = (const float*)d_in[0];
    const float* Rm      = (const float*)d_in[1];
    const float* Pm      = (const float*)d_in[2];
    const float* qkv_w   = (const float*)d_in[3];
    const float* qkv_b   = (const float*)d_in[4];
    const float* proj_w  = (const float*)d_in[5];
    const float* proj_b  = (const float*)d_in[6];
    const float* pos_scl = (const float*)d_in[7];
    float* out = (float*)d_out;

    float* qkv  = (float*)d_ws;                                   // 3*B*H*N*D f32 = 24 MB
    float* obuf = qkv + (size_t)3 * B_ * H_ * N_ * D_;            // B*H*N*D f32 = 8 MB

    qkv_kernel<<<dim3(128, 12), 256, 0, stream>>>(x, qkv_w, qkv_b, qkv);
    attn_kernel<<<dim3(32, 16), 256, 0, stream>>>(qkv, Rm, Pm, pos_scl, obuf);
    proj_kernel<<<dim3(128, 4), 256, 0, stream>>>(obuf, proj_w, proj_b, out);
}

// Round 4
// 186.272 us; speedup vs baseline: 2.4053x; 1.4732x over previous
//
#include <hip/hip_runtime.h>

#define B_ 4
#define N_ 2048
#define C_ 256
#define H_ 4
#define D_ 64

typedef __attribute__((ext_vector_type(8))) short bf16x8;
typedef __attribute__((ext_vector_type(4))) float f32x4;

// f32 -> bf16 round-to-nearest-even (scalar)
static __device__ inline unsigned short f2bf(float f) {
    unsigned u = __builtin_bit_cast(unsigned, f);
    unsigned r = (u + 0x7fffu + ((u >> 16) & 1u)) >> 16;
    return (unsigned short)r;
}
// packed pair f32 -> bf16x2 (lo = a, hi = b)
static __device__ inline unsigned pack2(float a, float b) {
    return (unsigned)f2bf(a) | ((unsigned)f2bf(b) << 16);
}
static __device__ inline bf16x8 ld_frag(const unsigned short* p) {
    return __builtin_bit_cast(bf16x8, *(const uint4*)p);
}

// ---------------- f32 -> bf16 conversion prepass ----------------
__global__ __launch_bounds__(256) void cvt_kernel(
    const float* __restrict__ s, unsigned short* __restrict__ d, int n)
{
    int i = (blockIdx.x * 256 + threadIdx.x) * 8;
    if (i >= n) return;
    float4 a = *(const float4*)(s + i);
    float4 b = *(const float4*)(s + i + 4);
    uint4 u;
    u.x = pack2(a.x, a.y); u.y = pack2(a.z, a.w);
    u.z = pack2(b.x, b.y); u.w = pack2(b.z, b.w);
    *(uint4*)(d + i) = u;
}

// ---------------- QKV GEMM (bf16 MFMA): S[m][o] = sum_k x[m][k] w[o][k] + b[o] ----
// 128x128 tile, 4 waves 2x2, BK=32. Emits bf16 Q/K/V as [b][h][n][d].
__global__ __launch_bounds__(256) void qkv_gemm(
    const unsigned short* __restrict__ xb, const unsigned short* __restrict__ wb,
    const float* __restrict__ bias, unsigned short* __restrict__ qb,
    unsigned short* __restrict__ kb, unsigned short* __restrict__ vb)
{
    __shared__ __align__(16) unsigned short As[128 * 40];  // row stride 40 bf16 (80 B): 2-way banks
    __shared__ __align__(16) unsigned short Bs[128 * 40];
    const int m0 = blockIdx.x * 128, o0 = blockIdx.y * 128;
    const int tid = threadIdx.x;
    const int wave = tid >> 6, lane = tid & 63, quad = lane >> 4, l16 = lane & 15;
    const int wy = wave >> 1, wx = wave & 1;

    f32x4 acc[4][4];
    #pragma unroll
    for (int i = 0; i < 4; ++i)
        #pragma unroll
        for (int j = 0; j < 4; ++j) acc[i][j] = (f32x4){0.f, 0.f, 0.f, 0.f};

    for (int k0 = 0; k0 < 256; k0 += 32) {
        __syncthreads();
        #pragma unroll
        for (int rr = 0; rr < 2; ++rr) {
            int c = tid + rr * 256;
            int row = c >> 2, off = (c & 3) * 8;
            *(uint4*)&As[row * 40 + off] = *(const uint4*)&xb[(size_t)(m0 + row) * 256 + k0 + off];
            *(uint4*)&Bs[row * 40 + off] = *(const uint4*)&wb[(size_t)(o0 + row) * 256 + k0 + off];
        }
        __syncthreads();
        bf16x8 a[4], b[4];
        #pragma unroll
        for (int mt = 0; mt < 4; ++mt) a[mt] = ld_frag(&As[(wy * 64 + mt * 16 + l16) * 40 + quad * 8]);
        #pragma unroll
        for (int nt = 0; nt < 4; ++nt) b[nt] = ld_frag(&Bs[(wx * 64 + nt * 16 + l16) * 40 + quad * 8]);
        #pragma unroll
        for (int mt = 0; mt < 4; ++mt)
            #pragma unroll
            for (int nt = 0; nt < 4; ++nt)
                acc[mt][nt] = __builtin_amdgcn_mfma_f32_16x16x32_bf16(a[mt], b[nt], acc[mt][nt], 0, 0, 0);
    }

    // epilogue: this wave's 64 cols live in one (three, h) section
    const int ocol0 = o0 + wx * 64;
    const int three = ocol0 >> 8;
    const int h = (ocol0 >> 6) & 3;
    unsigned short* dst = (three == 0) ? qb : (three == 1) ? kb : vb;
    float bv[4];
    #pragma unroll
    for (int nt = 0; nt < 4; ++nt) bv[nt] = bias[ocol0 + nt * 16 + l16];
    #pragma unroll
    for (int mt = 0; mt < 4; ++mt)
        #pragma unroll
        for (int r = 0; r < 4; ++r) {
            int m = m0 + wy * 64 + mt * 16 + quad * 4 + r;
            int bb = m >> 11, n = m & 2047;
            size_t rowbase = (((size_t)bb * H_ + h) * N_ + n) * D_;
            #pragma unroll
            for (int nt = 0; nt < 4; ++nt)
                dst[rowbase + nt * 16 + l16] = f2bf(acc[mt][nt][r] + bv[nt]);
        }
}

// ---------------- V transpose: [bh][n][d] -> [bh][d][n_perm] ----------------
// perm within each 64-key block: p = 4*(n&15) + ((n>>4)&3), so attn's packed-P
// positions k map to key(k) = (k>>2) + 16*(k&3).
__global__ __launch_bounds__(256) void vtrans_kernel(
    const unsigned short* __restrict__ vb, unsigned short* __restrict__ vt)
{
    __shared__ unsigned short Tt[64 * 72];
    const int bh = blockIdx.y, n0 = blockIdx.x * 64, tid = threadIdx.x;
    #pragma unroll
    for (int rr = 0; rr < 2; ++rr) {
        int c = tid + rr * 256;
        int nl = c >> 3, off = (c & 7) * 8;
        union { uint4 u; unsigned short s[8]; } tmp;
        tmp.u = *(const uint4*)&vb[((size_t)bh * N_ + n0 + nl) * 64 + off];
        int p = 4 * (nl & 15) + (nl >> 4);
        #pragma unroll
        for (int j = 0; j < 8; ++j) Tt[(off + j) * 72 + p] = tmp.s[j];
    }
    __syncthreads();
    #pragma unroll
    for (int rr = 0; rr < 2; ++rr) {
        int c = tid + rr * 256;
        int d = c >> 3, off = (c & 7) * 8;
        *(uint4*)&vt[((size_t)bh * 64 + d) * N_ + n0 + off] = *(const uint4*)&Tt[d * 72 + off];
    }
}

// ---------------- Flash attention, bf16 MFMA, bf16 staging ----------------
#define LDK 72

__global__ __launch_bounds__(256) void attn_kernel(
    const unsigned short* __restrict__ qb, const unsigned short* __restrict__ kb,
    const unsigned short* __restrict__ vt, const float* __restrict__ Rm,
    const float* __restrict__ Pm, const float* __restrict__ ps_ptr,
    unsigned short* __restrict__ obuf)
{
    __shared__ __align__(16) unsigned short Ks[64 * LDK];  // [key][d]
    __shared__ __align__(16) unsigned short Vs[64 * LDK];  // [d][key_perm]
    __shared__ __align__(16) unsigned short Ps[64 * LDK];  // [query][key_perm], packed

    const int bh = blockIdx.y;
    const int b = bh >> 2, h = bh & 3;
    const int i0 = blockIdx.x * 64;
    const int tid = threadIdx.x;
    const int wave = tid >> 6, lane = tid & 63;
    const int quad = lane >> 4, l16 = lane & 15;
    const float ps = ps_ptr[0];
    const float LOG2E = 1.4426950408889634f;
    const float k_scale = 0.125f * LOG2E;
    const float k_bias  = ps * LOG2E;

    const size_t base = (size_t)bh * N_ * D_;
    const unsigned short* qg = qb + base;
    const unsigned short* kg = kb + base;
    const unsigned short* vg = vt + base;   // rows of length N_

    // Q A-fragments straight from global (16B aligned)
    const int qrow = i0 + wave * 16 + l16;
    bf16x8 aq[2];
    #pragma unroll
    for (int ks = 0; ks < 2; ++ks)
        aq[ks] = ld_frag(&qg[(size_t)qrow * D_ + ks * 32 + quad * 8]);

    // rp = R_b @ P_i for this lane's 4 output rows (C-layout rows = quad*4+r)
    float rpr[4][3];
    #pragma unroll
    for (int r = 0; r < 4; ++r) {
        int qi = i0 + wave * 16 + quad * 4 + r;
        float p0 = Pm[qi * 3 + 0], p1 = Pm[qi * 3 + 1], p2 = Pm[qi * 3 + 2];
        #pragma unroll
        for (int c = 0; c < 3; ++c)
            rpr[r][c] = Rm[b * 9 + c * 3 + 0] * p0 + Rm[b * 9 + c * 3 + 1] * p1
                      + Rm[b * 9 + c * 3 + 2] * p2;
    }

    float m_i[4], l_i[4];
    #pragma unroll
    for (int r = 0; r < 4; ++r) { m_i[r] = -1e30f; l_i[r] = 0.f; }
    f32x4 o_acc[4];
    #pragma unroll
    for (int t = 0; t < 4; ++t) o_acc[t] = (f32x4){0.f, 0.f, 0.f, 0.f};

    for (int j0 = 0; j0 < N_; j0 += 64) {
        __syncthreads();
        // stage K [key][d] and Vt [d][key_perm] — pure b128 copies
        #pragma unroll
        for (int rr = 0; rr < 2; ++rr) {
            int c = tid + rr * 256;
            int row = c >> 3, off = (c & 7) * 8;
            *(uint4*)&Ks[row * LDK + off] = *(const uint4*)&kg[(size_t)(j0 + row) * D_ + off];
            *(uint4*)&Vs[row * LDK + off] = *(const uint4*)&vg[(size_t)row * N_ + j0 + off];
        }
        __syncthreads();

        // S = Q K^T (16 x 64 strip per wave)
        f32x4 s[4];
        #pragma unroll
        for (int t = 0; t < 4; ++t) {
            f32x4 c = {0.f, 0.f, 0.f, 0.f};
            #pragma unroll
            for (int ks = 0; ks < 2; ++ks) {
                bf16x8 bk = ld_frag(&Ks[(l16 + 16 * t) * LDK + ks * 32 + quad * 8]);
                c = __builtin_amdgcn_mfma_f32_16x16x32_bf16(aq[ks], bk, c, 0, 0, 0);
            }
            s[t] = c;
        }

        // bias + online softmax (log2 domain); logit row=quad*4+r, col=l16+16t
        float pj[4][3];
        #pragma unroll
        for (int t = 0; t < 4; ++t) {
            int col = j0 + l16 + 16 * t;
            pj[t][0] = Pm[col * 3 + 0]; pj[t][1] = Pm[col * 3 + 1]; pj[t][2] = Pm[col * 3 + 2];
        }
        float lg[4][4], alpha[4];
        #pragma unroll
        for (int r = 0; r < 4; ++r) {
            float mx = m_i[r];
            #pragma unroll
            for (int t = 0; t < 4; ++t) {
                float bias = rpr[r][0] * pj[t][0] + rpr[r][1] * pj[t][1] + rpr[r][2] * pj[t][2];
                float v = s[t][r] * k_scale + bias * k_bias;
                lg[r][t] = v;
                mx = fmaxf(mx, v);
            }
            mx = fmaxf(mx, __shfl_xor(mx, 1));
            mx = fmaxf(mx, __shfl_xor(mx, 2));
            mx = fmaxf(mx, __shfl_xor(mx, 4));
            mx = fmaxf(mx, __shfl_xor(mx, 8));
            alpha[r] = exp2f(m_i[r] - mx);
            float sm = 0.f;
            #pragma unroll
            for (int t = 0; t < 4; ++t) {
                float p = exp2f(lg[r][t] - mx);
                lg[r][t] = p;
                sm += p;
            }
            sm += __shfl_xor(sm, 1);
            sm += __shfl_xor(sm, 2);
            sm += __shfl_xor(sm, 4);
            sm += __shfl_xor(sm, 8);
            m_i[r] = mx;
            l_i[r] = l_i[r] * alpha[r] + sm;
        }

        // P -> Ps packed: position p = 4*l16 + t (matches Vt's key permutation)
        #pragma unroll
        for (int r = 0; r < 4; ++r) {
            uint2 w;
            w.x = pack2(lg[r][0], lg[r][1]);
            w.y = pack2(lg[r][2], lg[r][3]);
            *(uint2*)&Ps[(wave * 16 + quad * 4 + r) * LDK + 4 * l16] = w;
        }

        // rescale O
        #pragma unroll
        for (int t = 0; t < 4; ++t)
            #pragma unroll
            for (int r = 0; r < 4; ++r)
                o_acc[t][r] *= alpha[r];

        // O += P V (A = Ps rows, B = Vs rows; shared key permutation)
        #pragma unroll
        for (int ks = 0; ks < 2; ++ks) {
            bf16x8 ap = ld_frag(&Ps[(wave * 16 + l16) * LDK + ks * 32 + quad * 8]);
            #pragma unroll
            for (int t = 0; t < 4; ++t) {
                bf16x8 bv = ld_frag(&Vs[(l16 + 16 * t) * LDK + ks * 32 + quad * 8]);
                o_acc[t] = __builtin_amdgcn_mfma_f32_16x16x32_bf16(ap, bv, o_acc[t], 0, 0, 0);
            }
        }
    }

    // epilogue: normalize, store bf16 (B,N,C) with c = h*64 + d
    #pragma unroll
    for (int r = 0; r < 4; ++r) {
        float inv = 1.f / l_i[r];
        int row = i0 + wave * 16 + quad * 4 + r;
        #pragma unroll
        for (int t = 0; t < 4; ++t)
            obuf[((size_t)b * N_ + row) * C_ + h * 64 + l16 + 16 * t] = f2bf(o_acc[t][r] * inv);
    }
}

// ---------------- Output projection (bf16 MFMA): out = O @ Wp^T + b ----------------
// 128x64 tile, 4 waves stacked on M, BK=32, f32 output.
__global__ __launch_bounds__(256) void proj_gemm(
    const unsigned short* __restrict__ ob, const unsigned short* __restrict__ wb,
    const float* __restrict__ bias, float* __restrict__ out)
{
    __shared__ __align__(16) unsigned short As[128 * 40];
    __shared__ __align__(16) unsigned short Bs[64 * 40];
    const int m0 = blockIdx.x * 128, o0 = blockIdx.y * 64;
    const int tid = threadIdx.x;
    const int wave = tid >> 6, lane = tid & 63, quad = lane >> 4, l16 = lane & 15;

    f32x4 acc[2][4];
    #pragma unroll
    for (int i = 0; i < 2; ++i)
        #pragma unroll
        for (int j = 0; j < 4; ++j) acc[i][j] = (f32x4){0.f, 0.f, 0.f, 0.f};

    for (int k0 = 0; k0 < 256; k0 += 32) {
        __syncthreads();
        #pragma unroll
        for (int rr = 0; rr < 2; ++rr) {
            int c = tid + rr * 256;
            int row = c >> 2, off = (c & 3) * 8;
            *(uint4*)&As[row * 40 + off] = *(const uint4*)&ob[(size_t)(m0 + row) * 256 + k0 + off];
        }
        {
            int row = tid >> 2, off = (tid & 3) * 8;
            *(uint4*)&Bs[row * 40 + off] = *(const uint4*)&wb[(size_t)(o0 + row) * 256 + k0 + off];
        }
        __syncthreads();
        bf16x8 a[2], b[4];
        #pragma unroll
        for (int mt = 0; mt < 2; ++mt) a[mt] = ld_frag(&As[(wave * 32 + mt * 16 + l16) * 40 + quad * 8]);
        #pragma unroll
        for (int nt = 0; nt < 4; ++nt) b[nt] = ld_frag(&Bs[(nt * 16 + l16) * 40 + quad * 8]);
        #pragma unroll
        for (int mt = 0; mt < 2; ++mt)
            #pragma unroll
            for (int nt = 0; nt < 4; ++nt)
                acc[mt][nt] = __builtin_amdgcn_mfma_f32_16x16x32_bf16(a[mt], b[nt], acc[mt][nt], 0, 0, 0);
    }

    float bv[4];
    #pragma unroll
    for (int nt = 0; nt < 4; ++nt) bv[nt] = bias[o0 + nt * 16 + l16];
    #pragma unroll
    for (int mt = 0; mt < 2; ++mt)
        #pragma unroll
        for (int r = 0; r < 4; ++r) {
            int m = m0 + wave * 32 + mt * 16 + quad * 4 + r;
            #pragma unroll
            for (int nt = 0; nt < 4; ++nt)
                out[(size_t)m * 256 + o0 + nt * 16 + l16] = acc[mt][nt][r] + bv[nt];
        }
}

extern "C" void kernel_launch(void* const* d_in, const int* in_sizes, int n_in,
                              void* d_out, int out_size, void* d_ws, size_t ws_size,
                              hipStream_t stream) {
    const float* x       = (const float*)d_in[0];
    const float* Rm      = (const float*)d_in[1];
    const float* Pm      = (const float*)d_in[2];
    const float* qkv_w   = (const float*)d_in[3];
    const float* qkv_b   = (const float*)d_in[4];
    const float* proj_w  = (const float*)d_in[5];
    const float* proj_b  = (const float*)d_in[6];
    const float* pos_scl = (const float*)d_in[7];
    float* out = (float*)d_out;

    const size_t NE = (size_t)B_ * H_ * N_ * D_;   // 2,097,152
    unsigned short* xb   = (unsigned short*)d_ws;  // 8192*256
    unsigned short* wqb  = xb  + NE;               // 768*256
    unsigned short* wpb  = wqb + 768 * 256;        // 256*256
    unsigned short* qb   = wpb + 256 * 256;
    unsigned short* kb   = qb  + NE;
    unsigned short* vb   = kb  + NE;
    unsigned short* vtb  = vb  + NE;
    unsigned short* obuf = vtb + NE;               // total ~24.5 MB

    cvt_kernel<<<1024, 256, 0, stream>>>(x, xb, (int)NE);
    cvt_kernel<<<96, 256, 0, stream>>>(qkv_w, wqb, 768 * 256);
    cvt_kernel<<<32, 256, 0, stream>>>(proj_w, wpb, 256 * 256);
    qkv_gemm<<<dim3(64, 6), 256, 0, stream>>>(xb, wqb, qkv_b, qb, kb, vb);
    vtrans_kernel<<<dim3(32, 16), 256, 0, stream>>>(vb, vtb);
    attn_kernel<<<dim3(32, 16), 256, 0, stream>>>(qb, kb, vtb, Rm, Pm, pos_scl, obuf);
    proj_gemm<<<dim3(64, 4), 256, 0, stream>>>(obuf, wpb, proj_b, out);
}

// Round 5
// 164.848 us; speedup vs baseline: 2.7179x; 1.1300x over previous
//
#include <hip/hip_runtime.h>

#define B_ 4
#define N_ 2048
#define C_ 256
#define H_ 4
#define D_ 64

typedef __attribute__((ext_vector_type(8))) short bf16x8;
typedef __attribute__((ext_vector_type(4))) float f32x4;

#define LOG2E 1.4426950408889634f

// f32 -> bf16 round-to-nearest-even (scalar)
static __device__ inline unsigned short f2bf(float f) {
    unsigned u = __builtin_bit_cast(unsigned, f);
    unsigned r = (u + 0x7fffu + ((u >> 16) & 1u)) >> 16;
    return (unsigned short)r;
}
static __device__ inline float bf2f(unsigned short h) {
    unsigned u = ((unsigned)h) << 16;
    return __builtin_bit_cast(float, u);
}
// packed pair f32 -> bf16x2 (lo = a, hi = b)
static __device__ inline unsigned pack2(float a, float b) {
    return (unsigned)f2bf(a) | ((unsigned)f2bf(b) << 16);
}
static __device__ inline bf16x8 ld_frag(const unsigned short* p) {
    return __builtin_bit_cast(bf16x8, *(const uint4*)p);
}

// ---------------- P extension table: Pext[n][32] = [u0,u1,u2,v0,v1,v2,u0,u1,u2,0..]
// u = bf16_hi(P), v = bf16_lo(P) — gives near-f32 accuracy for the bias MFMA.
__global__ __launch_bounds__(256) void pext_kernel(
    const float* __restrict__ Pm, unsigned short* __restrict__ Pext)
{
    int n = blockIdx.x * 256 + threadIdx.x;
    if (n >= N_) return;
    unsigned short row[32];
    #pragma unroll
    for (int i = 0; i < 32; ++i) row[i] = 0;
    #pragma unroll
    for (int c = 0; c < 3; ++c) {
        float p = Pm[n * 3 + c];
        unsigned short u = f2bf(p);
        unsigned short v = f2bf(p - bf2f(u));
        row[c] = u; row[3 + c] = v; row[6 + c] = u;
    }
    #pragma unroll
    for (int q = 0; q < 4; ++q)
        *(uint4*)&Pext[(size_t)n * 32 + q * 8] = *(const uint4*)&row[q * 8];
}

// ---------------- QKV GEMM (f32 in, bf16 MFMA): 128x64 tile, 4 waves on M ----
// Q pre-scaled by 0.125*log2e. V written directly transposed+permuted:
// vt[bh][d][n_perm], perm within 64-block: p = 4*(n&15) + (n>>4).
__global__ __launch_bounds__(256) void qkv_gemm(
    const float* __restrict__ x, const float* __restrict__ w,
    const float* __restrict__ bias, unsigned short* __restrict__ qb,
    unsigned short* __restrict__ kb, unsigned short* __restrict__ vt)
{
    __shared__ __align__(16) unsigned short As[128 * 40];
    __shared__ __align__(16) unsigned short Bs[64 * 40];
    const int m0 = blockIdx.x * 128, o0 = blockIdx.y * 64;
    const int tid = threadIdx.x;
    const int wave = tid >> 6, lane = tid & 63, quad = lane >> 4, l16 = lane & 15;

    f32x4 acc[2][4];
    #pragma unroll
    for (int i = 0; i < 2; ++i)
        #pragma unroll
        for (int j = 0; j < 4; ++j) acc[i][j] = (f32x4){0.f, 0.f, 0.f, 0.f};

    for (int k0 = 0; k0 < 256; k0 += 32) {
        __syncthreads();
        {   // A: 128x32 f32 -> bf16
            int row = tid >> 1, cb = (tid & 1) * 16;
            const float* src = &x[(size_t)(m0 + row) * 256 + k0 + cb];
            float4 a0 = *(const float4*)(src + 0);
            float4 a1 = *(const float4*)(src + 4);
            float4 a2 = *(const float4*)(src + 8);
            float4 a3 = *(const float4*)(src + 12);
            uint4 u0, u1;
            u0.x = pack2(a0.x, a0.y); u0.y = pack2(a0.z, a0.w);
            u0.z = pack2(a1.x, a1.y); u0.w = pack2(a1.z, a1.w);
            u1.x = pack2(a2.x, a2.y); u1.y = pack2(a2.z, a2.w);
            u1.z = pack2(a3.x, a3.y); u1.w = pack2(a3.z, a3.w);
            *(uint4*)&As[row * 40 + cb + 0] = u0;
            *(uint4*)&As[row * 40 + cb + 8] = u1;
        }
        {   // B: 64x32 f32 -> bf16
            int row = tid >> 2, cb = (tid & 3) * 8;
            const float* src = &w[(size_t)(o0 + row) * 256 + k0 + cb];
            float4 b0 = *(const float4*)(src + 0);
            float4 b1 = *(const float4*)(src + 4);
            uint4 u;
            u.x = pack2(b0.x, b0.y); u.y = pack2(b0.z, b0.w);
            u.z = pack2(b1.x, b1.y); u.w = pack2(b1.z, b1.w);
            *(uint4*)&Bs[row * 40 + cb] = u;
        }
        __syncthreads();
        bf16x8 a[2], b[4];
        #pragma unroll
        for (int mt = 0; mt < 2; ++mt) a[mt] = ld_frag(&As[(wave * 32 + mt * 16 + l16) * 40 + quad * 8]);
        #pragma unroll
        for (int nt = 0; nt < 4; ++nt) b[nt] = ld_frag(&Bs[(nt * 16 + l16) * 40 + quad * 8]);
        #pragma unroll
        for (int mt = 0; mt < 2; ++mt)
            #pragma unroll
            for (int nt = 0; nt < 4; ++nt)
                acc[mt][nt] = __builtin_amdgcn_mfma_f32_16x16x32_bf16(a[mt], b[nt], acc[mt][nt], 0, 0, 0);
    }

    const int three = o0 >> 8;
    const int h = (o0 >> 6) & 3;
    const int b = m0 >> 11;
    const float qscale = 0.125f * LOG2E;
    float bv[4];
    #pragma unroll
    for (int nt = 0; nt < 4; ++nt) bv[nt] = bias[o0 + nt * 16 + l16];

    if (three == 2) {
        // V: write transposed+permuted: p = 16*quad + 4*r + 2*(wave&1) + mt
        const int n64 = ((m0 + (wave >> 1) * 64) & 2047);
        const size_t bh64 = ((size_t)b * H_ + h) * 64;
        #pragma unroll
        for (int nt = 0; nt < 4; ++nt) {
            int d = nt * 16 + l16;
            #pragma unroll
            for (int r = 0; r < 4; ++r) {
                unsigned pw = pack2(acc[0][nt][r] + bv[nt], acc[1][nt][r] + bv[nt]);
                *(unsigned*)&vt[(bh64 + d) * N_ + n64 + 16 * quad + 4 * r + 2 * (wave & 1)] = pw;
            }
        }
    } else {
        unsigned short* dst = (three == 0) ? qb : kb;
        float sc = (three == 0) ? qscale : 1.0f;
        #pragma unroll
        for (int mt = 0; mt < 2; ++mt)
            #pragma unroll
            for (int r = 0; r < 4; ++r) {
                int m = m0 + wave * 32 + mt * 16 + quad * 4 + r;
                int n = m & 2047;
                size_t rowbase = (((size_t)b * H_ + h) * N_ + n) * D_;
                #pragma unroll
                for (int nt = 0; nt < 4; ++nt)
                    dst[rowbase + nt * 16 + l16] = f2bf((acc[mt][nt][r] + bv[nt]) * sc);
            }
    }
}

// ---------------- Flash attention: bias folded into MFMA, split-K x2 ----------------
#define LDK 72
#define LDKX 104   // Ks row: 64 d + 32 ext + 8 pad

__global__ __launch_bounds__(256) void attn_kernel(
    const unsigned short* __restrict__ qb, const unsigned short* __restrict__ kb,
    const unsigned short* __restrict__ vt, const unsigned short* __restrict__ Pext,
    const float* __restrict__ Rm, const float* __restrict__ Pm,
    const float* __restrict__ ps_ptr,
    unsigned short* __restrict__ Opart, float* __restrict__ ml)
{
    __shared__ __align__(16) unsigned short Ks[64 * LDKX]; // [key][d | ext]
    __shared__ __align__(16) unsigned short Vs[64 * LDK];  // [d][key_perm]
    __shared__ __align__(16) unsigned short Ps[64 * LDK];  // [query][key_perm]

    const int bh = blockIdx.y;
    const int b = bh >> 2;
    const int i0 = blockIdx.x * 64;
    const int split = blockIdx.z;
    const int tid = threadIdx.x;
    const int wave = tid >> 6, lane = tid & 63;
    const int quad = lane >> 4, l16 = lane & 15;
    const float ps = ps_ptr[0];

    const size_t base = (size_t)bh * N_ * D_;
    const unsigned short* qg = qb + base;
    const unsigned short* kg = kb + base;
    const unsigned short* vg = vt + base;   // rows of length N_

    // Q A-fragments (pre-scaled by 0.125*log2e in qkv epilogue)
    const int qrow = i0 + wave * 16 + l16;
    bf16x8 aq[3];
    #pragma unroll
    for (int ks = 0; ks < 2; ++ks)
        aq[ks] = ld_frag(&qg[(size_t)qrow * D_ + ks * 32 + quad * 8]);

    // A-side bias ext: a = ps*log2e*(R_b @ P_qrow), hi/lo split.
    {
        float p0 = Pm[qrow * 3 + 0], p1 = Pm[qrow * 3 + 1], p2 = Pm[qrow * 3 + 2];
        float sc = ps * LOG2E;
        unsigned short ah[3], al[3];
        #pragma unroll
        for (int c = 0; c < 3; ++c) {
            float a = (Rm[b * 9 + c * 3 + 0] * p0 + Rm[b * 9 + c * 3 + 1] * p1
                     + Rm[b * 9 + c * 3 + 2] * p2) * sc;
            ah[c] = f2bf(a);
            al[c] = f2bf(a - bf2f(ah[c]));
        }
        bf16x8 e = (bf16x8){0,0,0,0,0,0,0,0};
        if (quad == 0) {
            e[0] = (short)ah[0]; e[1] = (short)ah[1]; e[2] = (short)ah[2];
            e[3] = (short)ah[0]; e[4] = (short)ah[1]; e[5] = (short)ah[2];
            e[6] = (short)al[0]; e[7] = (short)al[1];
        } else if (quad == 1) {
            e[0] = (short)al[2];
        }
        aq[2] = e;
    }

    float m_i[4], l_i[4];
    #pragma unroll
    for (int r = 0; r < 4; ++r) { m_i[r] = -1e30f; l_i[r] = 0.f; }
    f32x4 o_acc[4];
    #pragma unroll
    for (int t = 0; t < 4; ++t) o_acc[t] = (f32x4){0.f, 0.f, 0.f, 0.f};

    const int jbeg = split * (N_ / 2);
    for (int jt = 0; jt < (N_ / 2) / 64; ++jt) {
        const int j0 = jbeg + jt * 64;
        __syncthreads();
        // stage K [key][d], Vt [d][key_perm] (b128 copies), ext from Pext
        #pragma unroll
        for (int rr = 0; rr < 2; ++rr) {
            int c = tid + rr * 256;
            int row = c >> 3, off = (c & 7) * 8;
            *(uint4*)&Ks[row * LDKX + off] = *(const uint4*)&kg[(size_t)(j0 + row) * D_ + off];
            *(uint4*)&Vs[row * LDK + off] = *(const uint4*)&vg[(size_t)row * N_ + j0 + off];
        }
        {
            int row = tid >> 2, q4 = tid & 3;
            *(uint4*)&Ks[row * LDKX + 64 + q4 * 8] = *(const uint4*)&Pext[(size_t)(j0 + row) * 32 + q4 * 8];
        }
        __syncthreads();

        // S (log2-domain logits incl. bias): 3 k-steps
        f32x4 s[4];
        #pragma unroll
        for (int t = 0; t < 4; ++t) {
            f32x4 c = {0.f, 0.f, 0.f, 0.f};
            #pragma unroll
            for (int ks = 0; ks < 3; ++ks) {
                bf16x8 bk = ld_frag(&Ks[(l16 + 16 * t) * LDKX + ks * 32 + quad * 8]);
                c = __builtin_amdgcn_mfma_f32_16x16x32_bf16(aq[ks], bk, c, 0, 0, 0);
            }
            s[t] = c;
        }

        // online softmax in log2 domain; row = quad*4+r, col = l16+16t
        float lg[4][4], alpha[4];
        #pragma unroll
        for (int r = 0; r < 4; ++r) {
            float mx = m_i[r];
            #pragma unroll
            for (int t = 0; t < 4; ++t) {
                lg[r][t] = s[t][r];
                mx = fmaxf(mx, s[t][r]);
            }
            mx = fmaxf(mx, __shfl_xor(mx, 1));
            mx = fmaxf(mx, __shfl_xor(mx, 2));
            mx = fmaxf(mx, __shfl_xor(mx, 4));
            mx = fmaxf(mx, __shfl_xor(mx, 8));
            alpha[r] = exp2f(m_i[r] - mx);
            float sm = 0.f;
            #pragma unroll
            for (int t = 0; t < 4; ++t) {
                float p = exp2f(lg[r][t] - mx);
                lg[r][t] = p;
                sm += p;
            }
            sm += __shfl_xor(sm, 1);
            sm += __shfl_xor(sm, 2);
            sm += __shfl_xor(sm, 4);
            sm += __shfl_xor(sm, 8);
            m_i[r] = mx;
            l_i[r] = l_i[r] * alpha[r] + sm;
        }

        // P -> Ps packed at position p = 4*l16 + t (matches V's key perm)
        #pragma unroll
        for (int r = 0; r < 4; ++r) {
            uint2 w;
            w.x = pack2(lg[r][0], lg[r][1]);
            w.y = pack2(lg[r][2], lg[r][3]);
            *(uint2*)&Ps[(wave * 16 + quad * 4 + r) * LDK + 4 * l16] = w;
        }

        // rescale O
        #pragma unroll
        for (int t = 0; t < 4; ++t)
            #pragma unroll
            for (int r = 0; r < 4; ++r)
                o_acc[t][r] *= alpha[r];

        // O += P V
        #pragma unroll
        for (int ks = 0; ks < 2; ++ks) {
            bf16x8 ap = ld_frag(&Ps[(wave * 16 + l16) * LDK + ks * 32 + quad * 8]);
            #pragma unroll
            for (int t = 0; t < 4; ++t) {
                bf16x8 bv = ld_frag(&Vs[(l16 + 16 * t) * LDK + ks * 32 + quad * 8]);
                o_acc[t] = __builtin_amdgcn_mfma_f32_16x16x32_bf16(ap, bv, o_acc[t], 0, 0, 0);
            }
        }
    }

    // store unnormalized partial O (bf16) + (m,l) per row
    const size_t pbase = ((size_t)(split * 16 + bh) * N_) ;
    #pragma unroll
    for (int r = 0; r < 4; ++r) {
        int row = i0 + wave * 16 + quad * 4 + r;
        #pragma unroll
        for (int t = 0; t < 4; ++t)
            Opart[(pbase + row) * D_ + l16 + 16 * t] = f2bf(o_acc[t][r]);
        if (l16 == 0) {
            float2* mlp = (float2*)ml;
            mlp[pbase + row] = make_float2(m_i[r], l_i[r]);
        }
    }
}

// ---------------- Merge split-K partials -> obuf bf16 (B,N,C), c = h*64+d ----------
__global__ __launch_bounds__(256) void merge_kernel(
    const unsigned short* __restrict__ Opart, const float* __restrict__ ml,
    unsigned short* __restrict__ obuf)
{
    int cid = blockIdx.x * 256 + threadIdx.x;   // 32768 rows * 8 chunks
    int bh = cid >> 14;
    int rem = cid & 16383;
    int n = rem >> 3;
    int d0 = (rem & 7) * 8;
    const float2* mlp = (const float2*)ml;
    size_t r1 = (size_t)bh * N_ + n;
    size_t r2 = (size_t)(16 + bh) * N_ + n;
    float2 ml1 = mlp[r1], ml2 = mlp[r2];
    float m = fmaxf(ml1.x, ml2.x);
    float w1 = exp2f(ml1.x - m), w2 = exp2f(ml2.x - m);
    float inv = 1.f / (ml1.y * w1 + ml2.y * w2);
    union { uint4 u; unsigned short s[8]; } a1, a2;
    a1.u = *(const uint4*)&Opart[r1 * D_ + d0];
    a2.u = *(const uint4*)&Opart[r2 * D_ + d0];
    int b = bh >> 2, h = bh & 3;
    unsigned short outv[8];
    #pragma unroll
    for (int j = 0; j < 8; ++j)
        outv[j] = f2bf((bf2f(a1.s[j]) * w1 + bf2f(a2.s[j]) * w2) * inv);
    *(uint4*)&obuf[(((size_t)b * N_ + n) * C_) + h * 64 + d0] = *(const uint4*)outv;
}

// ---------------- Output projection: 64x64 tile, 4 waves on M, f32 out ----------
__global__ __launch_bounds__(256) void proj_gemm(
    const unsigned short* __restrict__ ob, const float* __restrict__ w,
    const float* __restrict__ bias, float* __restrict__ out)
{
    __shared__ __align__(16) unsigned short As[64 * 40];
    __shared__ __align__(16) unsigned short Bs[64 * 40];
    const int m0 = blockIdx.x * 64, o0 = blockIdx.y * 64;
    const int tid = threadIdx.x;
    const int wave = tid >> 6, lane = tid & 63, quad = lane >> 4, l16 = lane & 15;

    f32x4 acc[4];
    #pragma unroll
    for (int j = 0; j < 4; ++j) acc[j] = (f32x4){0.f, 0.f, 0.f, 0.f};

    for (int k0 = 0; k0 < 256; k0 += 32) {
        __syncthreads();
        {   // A: 64x32 bf16 copy
            int row = tid >> 2, cb = (tid & 3) * 8;
            *(uint4*)&As[row * 40 + cb] = *(const uint4*)&ob[(size_t)(m0 + row) * 256 + k0 + cb];
        }
        {   // B: 64x32 f32 -> bf16
            int row = tid >> 2, cb = (tid & 3) * 8;
            const float* src = &w[(size_t)(o0 + row) * 256 + k0 + cb];
            float4 b0 = *(const float4*)(src + 0);
            float4 b1 = *(const float4*)(src + 4);
            uint4 u;
            u.x = pack2(b0.x, b0.y); u.y = pack2(b0.z, b0.w);
            u.z = pack2(b1.x, b1.y); u.w = pack2(b1.z, b1.w);
            *(uint4*)&Bs[row * 40 + cb] = u;
        }
        __syncthreads();
        bf16x8 a = ld_frag(&As[(wave * 16 + l16) * 40 + quad * 8]);
        #pragma unroll
        for (int nt = 0; nt < 4; ++nt) {
            bf16x8 b = ld_frag(&Bs[(nt * 16 + l16) * 40 + quad * 8]);
            acc[nt] = __builtin_amdgcn_mfma_f32_16x16x32_bf16(a, b, acc[nt], 0, 0, 0);
        }
    }

    float bv[4];
    #pragma unroll
    for (int nt = 0; nt < 4; ++nt) bv[nt] = bias[o0 + nt * 16 + l16];
    #pragma unroll
    for (int r = 0; r < 4; ++r) {
        int m = m0 + wave * 16 + quad * 4 + r;
        #pragma unroll
        for (int nt = 0; nt < 4; ++nt)
            out[(size_t)m * 256 + o0 + nt * 16 + l16] = acc[nt][r] + bv[nt];
    }
}

extern "C" void kernel_launch(void* const* d_in, const int* in_sizes, int n_in,
                              void* d_out, int out_size, void* d_ws, size_t ws_size,
                              hipStream_t stream) {
    const float* x       = (const float*)d_in[0];
    const float* Rm      = (const float*)d_in[1];
    const float* Pm      = (const float*)d_in[2];
    const float* qkv_w   = (const float*)d_in[3];
    const float* qkv_b   = (const float*)d_in[4];
    const float* proj_w  = (const float*)d_in[5];
    const float* proj_b  = (const float*)d_in[6];
    const float* pos_scl = (const float*)d_in[7];
    float* out = (float*)d_out;

    const size_t NE = (size_t)B_ * H_ * N_ * D_;   // 2,097,152
    unsigned short* qb    = (unsigned short*)d_ws; // each NE bf16 = 4 MB
    unsigned short* kb    = qb  + NE;
    unsigned short* vtb   = kb  + NE;
    unsigned short* pext  = vtb + NE;              // 2048*32 bf16 = 128 KB
    unsigned short* opart = pext + 2048 * 32;      // 2*NE bf16 = 8 MB
    float*          mlb   = (float*)(opart + 2 * NE);  // 2*16*2048*2 f32 = 512 KB
    unsigned short* obuf  = (unsigned short*)(mlb + 2 * 16 * 2048 * 2);  // NE bf16 = 4 MB

    pext_kernel<<<8, 256, 0, stream>>>(Pm, pext);
    qkv_gemm<<<dim3(64, 12), 256, 0, stream>>>(x, qkv_w, qkv_b, qb, kb, vtb);
    attn_kernel<<<dim3(32, 16, 2), 256, 0, stream>>>(qb, kb, vtb, pext, Rm, Pm, pos_scl, opart, mlb);
    merge_kernel<<<1024, 256, 0, stream>>>(opart, mlb, obuf);
    proj_gemm<<<dim3(128, 4), 256, 0, stream>>>(obuf, proj_w, proj_b, out);
}

// Round 6
// 147.826 us; speedup vs baseline: 3.0309x; 1.1152x over previous
//
#include <hip/hip_runtime.h>
#include <hip/hip_bf16.h>

#define B_ 4
#define N_ 2048
#define C_ 256
#define H_ 4
#define D_ 64

typedef __attribute__((ext_vector_type(8))) short bf16x8;
typedef __attribute__((ext_vector_type(4))) float f32x4;

#define LOG2E 1.4426950408889634f

// f32 -> bf16 round-to-nearest-even (scalar)
static __device__ inline unsigned short f2bf(float f) {
    unsigned u = __builtin_bit_cast(unsigned, f);
    unsigned r = (u + 0x7fffu + ((u >> 16) & 1u)) >> 16;
    return (unsigned short)r;
}
static __device__ inline float bf2f(unsigned short h) {
    unsigned u = ((unsigned)h) << 16;
    return __builtin_bit_cast(float, u);
}
// packed pair f32 -> bf16x2 via HIP header (single cvt_pk where available)
static __device__ inline unsigned pack2(float a, float b) {
    __hip_bfloat162 h = __float22bfloat162_rn(make_float2(a, b));
    unsigned u;
    __builtin_memcpy(&u, &h, 4);
    return u;
}
static __device__ inline bf16x8 ld_frag(const unsigned short* p) {
    return __builtin_bit_cast(bf16x8, *(const uint4*)p);
}

// ---------------- prep: convert x/qkv_w/proj_w to bf16, build Pext ----------------
// Pext[n][32] = [u0,u1,u2,v0,v1,v2,u0,u1,u2,0..], u=hi(P), v=lo(P)
__global__ __launch_bounds__(256) void prep_kernel(
    const float* __restrict__ x, const float* __restrict__ qkv_w,
    const float* __restrict__ proj_w, const float* __restrict__ Pm,
    unsigned short* __restrict__ xb, unsigned short* __restrict__ wqb,
    unsigned short* __restrict__ wpb, unsigned short* __restrict__ Pext)
{
    const int bid = blockIdx.x, tid = threadIdx.x;
    const float* s; unsigned short* d; int i;
    if (bid < 1024)      { s = x;      d = xb;  i = (bid * 256 + tid) * 8; }
    else if (bid < 1120) { s = qkv_w;  d = wqb; i = ((bid - 1024) * 256 + tid) * 8; }
    else if (bid < 1152) { s = proj_w; d = wpb; i = ((bid - 1120) * 256 + tid) * 8; }
    else {
        int n = (bid - 1152) * 256 + tid;
        if (n >= N_) return;
        unsigned short row[32];
        #pragma unroll
        for (int q = 0; q < 32; ++q) row[q] = 0;
        #pragma unroll
        for (int c = 0; c < 3; ++c) {
            float p = Pm[n * 3 + c];
            unsigned short u = f2bf(p);
            unsigned short v = f2bf(p - bf2f(u));
            row[c] = u; row[3 + c] = v; row[6 + c] = u;
        }
        #pragma unroll
        for (int q = 0; q < 4; ++q)
            *(uint4*)&Pext[(size_t)n * 32 + q * 8] = *(const uint4*)&row[q * 8];
        return;
    }
    float4 a = *(const float4*)(s + i);
    float4 b = *(const float4*)(s + i + 4);
    uint4 u;
    u.x = pack2(a.x, a.y); u.y = pack2(a.z, a.w);
    u.z = pack2(b.x, b.y); u.w = pack2(b.z, b.w);
    *(uint4*)(d + i) = u;
}

// ---------------- QKV GEMM (bf16 in/out): 128x64 tile, 4 waves on M ----------
// Q pre-scaled by 0.125*log2e. V written transposed+permuted:
// vt[bh][d][n_perm], perm within 64-block: p = 4*(n&15) + (n>>4).
__global__ __launch_bounds__(256) void qkv_gemm(
    const unsigned short* __restrict__ xb, const unsigned short* __restrict__ wb,
    const float* __restrict__ bias, unsigned short* __restrict__ qb,
    unsigned short* __restrict__ kb, unsigned short* __restrict__ vt)
{
    __shared__ __align__(16) unsigned short As[128 * 40];
    __shared__ __align__(16) unsigned short Bs[64 * 40];
    const int m0 = blockIdx.x * 128, o0 = blockIdx.y * 64;
    const int tid = threadIdx.x;
    const int wave = tid >> 6, lane = tid & 63, quad = lane >> 4, l16 = lane & 15;

    f32x4 acc[2][4];
    #pragma unroll
    for (int i = 0; i < 2; ++i)
        #pragma unroll
        for (int j = 0; j < 4; ++j) acc[i][j] = (f32x4){0.f, 0.f, 0.f, 0.f};

    for (int k0 = 0; k0 < 256; k0 += 32) {
        __syncthreads();
        {   // A: 128x32 bf16 copy (2 x b128 per thread)
            int row = tid >> 1, cb = (tid & 1) * 16;
            const unsigned short* src = &xb[(size_t)(m0 + row) * 256 + k0 + cb];
            *(uint4*)&As[row * 40 + cb + 0] = *(const uint4*)(src + 0);
            *(uint4*)&As[row * 40 + cb + 8] = *(const uint4*)(src + 8);
        }
        {   // B: 64x32 bf16 copy (1 x b128 per thread)
            int row = tid >> 2, cb = (tid & 3) * 8;
            *(uint4*)&Bs[row * 40 + cb] = *(const uint4*)&wb[(size_t)(o0 + row) * 256 + k0 + cb];
        }
        __syncthreads();
        bf16x8 a[2], b[4];
        #pragma unroll
        for (int mt = 0; mt < 2; ++mt) a[mt] = ld_frag(&As[(wave * 32 + mt * 16 + l16) * 40 + quad * 8]);
        #pragma unroll
        for (int nt = 0; nt < 4; ++nt) b[nt] = ld_frag(&Bs[(nt * 16 + l16) * 40 + quad * 8]);
        #pragma unroll
        for (int mt = 0; mt < 2; ++mt)
            #pragma unroll
            for (int nt = 0; nt < 4; ++nt)
                acc[mt][nt] = __builtin_amdgcn_mfma_f32_16x16x32_bf16(a[mt], b[nt], acc[mt][nt], 0, 0, 0);
    }

    const int three = o0 >> 8;
    const int h = (o0 >> 6) & 3;
    const int b = m0 >> 11;
    float bv[4];
    #pragma unroll
    for (int nt = 0; nt < 4; ++nt) bv[nt] = bias[o0 + nt * 16 + l16];

    if (three == 2) {
        // V: transposed+permuted; value for n = m0+wave*32+mt*16+quad*4+r lands at
        // n64 + 16*quad + 4*r + 2*(wave&1) + mt
        const int n64 = ((m0 + (wave >> 1) * 64) & 2047);
        const size_t bh64 = ((size_t)b * H_ + h) * 64;
        #pragma unroll
        for (int nt = 0; nt < 4; ++nt) {
            int d = nt * 16 + l16;
            #pragma unroll
            for (int r = 0; r < 4; ++r) {
                unsigned pw = pack2(acc[0][nt][r] + bv[nt], acc[1][nt][r] + bv[nt]);
                *(unsigned*)&vt[(bh64 + d) * N_ + n64 + 16 * quad + 4 * r + 2 * (wave & 1)] = pw;
            }
        }
    } else {
        unsigned short* dst = (three == 0) ? qb : kb;
        float sc = (three == 0) ? (0.125f * LOG2E) : 1.0f;
        #pragma unroll
        for (int mt = 0; mt < 2; ++mt)
            #pragma unroll
            for (int r = 0; r < 4; ++r) {
                int m = m0 + wave * 32 + mt * 16 + quad * 4 + r;
                int n = m & 2047;
                size_t rowbase = (((size_t)b * H_ + h) * N_ + n) * D_;
                #pragma unroll
                for (int nt = 0; nt < 4; ++nt)
                    dst[rowbase + nt * 16 + l16] = f2bf((acc[mt][nt][r] + bv[nt]) * sc);
            }
    }
}

// ---------------- Flash attention: bias in MFMA, strip-scalar softmax, l via ones-MFMA
#define LDK 72
#define LDKX 104   // Ks row: 64 d + 32 ext + 8 pad

__global__ __launch_bounds__(256) void attn_kernel(
    const unsigned short* __restrict__ qb, const unsigned short* __restrict__ kb,
    const unsigned short* __restrict__ vt, const unsigned short* __restrict__ Pext,
    const float* __restrict__ Rm, const float* __restrict__ Pm,
    const float* __restrict__ ps_ptr,
    unsigned short* __restrict__ Opart, float* __restrict__ ml)
{
    __shared__ __align__(16) unsigned short Ks[64 * LDKX]; // [key][d | ext]
    __shared__ __align__(16) unsigned short Vs[64 * LDK];  // [d][key_perm]
    __shared__ __align__(16) unsigned short Ps[64 * LDK];  // [query][key_perm]

    const int bh = blockIdx.y;
    const int b = bh >> 2;
    const int i0 = blockIdx.x * 64;
    const int split = blockIdx.z;
    const int tid = threadIdx.x;
    const int wave = tid >> 6, lane = tid & 63;
    const int quad = lane >> 4, l16 = lane & 15;
    const float ps = ps_ptr[0];

    const size_t base = (size_t)bh * N_ * D_;
    const unsigned short* qg = qb + base;
    const unsigned short* kg = kb + base;
    const unsigned short* vg = vt + base;   // rows of length N_

    // Q A-fragments (pre-scaled by 0.125*log2e)
    const int qrow = i0 + wave * 16 + l16;
    bf16x8 aq[3];
    #pragma unroll
    for (int ks = 0; ks < 2; ++ks)
        aq[ks] = ld_frag(&qg[(size_t)qrow * D_ + ks * 32 + quad * 8]);

    // A-side bias ext: a = ps*log2e*(R_b @ P_qrow), hi/lo split
    {
        float p0 = Pm[qrow * 3 + 0], p1 = Pm[qrow * 3 + 1], p2 = Pm[qrow * 3 + 2];
        float sc = ps * LOG2E;
        unsigned short ah[3], al[3];
        #pragma unroll
        for (int c = 0; c < 3; ++c) {
            float a = (Rm[b * 9 + c * 3 + 0] * p0 + Rm[b * 9 + c * 3 + 1] * p1
                     + Rm[b * 9 + c * 3 + 2] * p2) * sc;
            ah[c] = f2bf(a);
            al[c] = f2bf(a - bf2f(ah[c]));
        }
        bf16x8 e = (bf16x8){0,0,0,0,0,0,0,0};
        if (quad == 0) {
            e[0] = (short)ah[0]; e[1] = (short)ah[1]; e[2] = (short)ah[2];
            e[3] = (short)ah[0]; e[4] = (short)ah[1]; e[5] = (short)ah[2];
            e[6] = (short)al[0]; e[7] = (short)al[1];
        } else if (quad == 1) {
            e[0] = (short)al[2];
        }
        aq[2] = e;
    }

    const bf16x8 ones = (bf16x8){0x3F80,0x3F80,0x3F80,0x3F80,0x3F80,0x3F80,0x3F80,0x3F80};

    float m_run = -1e30f;
    f32x4 o_acc[4], lacc;
    #pragma unroll
    for (int t = 0; t < 4; ++t) o_acc[t] = (f32x4){0.f, 0.f, 0.f, 0.f};
    lacc = (f32x4){0.f, 0.f, 0.f, 0.f};

    const int jbeg = split * (N_ / 2);
    for (int jt = 0; jt < (N_ / 2) / 64; ++jt) {
        const int j0 = jbeg + jt * 64;
        __syncthreads();
        #pragma unroll
        for (int rr = 0; rr < 2; ++rr) {
            int c = tid + rr * 256;
            int row = c >> 3, off = (c & 7) * 8;
            *(uint4*)&Ks[row * LDKX + off] = *(const uint4*)&kg[(size_t)(j0 + row) * D_ + off];
            *(uint4*)&Vs[row * LDK + off] = *(const uint4*)&vg[(size_t)row * N_ + j0 + off];
        }
        {
            int row = tid >> 2, q4 = tid & 3;
            *(uint4*)&Ks[row * LDKX + 64 + q4 * 8] = *(const uint4*)&Pext[(size_t)(j0 + row) * 32 + q4 * 8];
        }
        __syncthreads();

        // S (log2-domain logits incl. bias): 3 k-steps x 4 col-tiles
        f32x4 s[4];
        #pragma unroll
        for (int t = 0; t < 4; ++t) {
            f32x4 c = {0.f, 0.f, 0.f, 0.f};
            #pragma unroll
            for (int ks = 0; ks < 3; ++ks) {
                bf16x8 bk = ld_frag(&Ks[(l16 + 16 * t) * LDKX + ks * 32 + quad * 8]);
                c = __builtin_amdgcn_mfma_f32_16x16x32_bf16(aq[ks], bk, c, 0, 0, 0);
            }
            s[t] = c;
        }

        // strip-scalar max over the wave's 16x64 logits
        float mx = m_run;
        #pragma unroll
        for (int t = 0; t < 4; ++t)
            #pragma unroll
            for (int r = 0; r < 4; ++r)
                mx = fmaxf(mx, s[t][r]);
        #pragma unroll
        for (int off = 1; off < 64; off <<= 1)
            mx = fmaxf(mx, __shfl_xor(mx, off));
        const float alpha = exp2f(m_run - mx);
        m_run = mx;

        // p = exp2(lg - mx); pack into Ps at position 4*l16 + t (matches V perm)
        #pragma unroll
        for (int r = 0; r < 4; ++r) {
            float p0 = exp2f(s[0][r] - mx), p1 = exp2f(s[1][r] - mx);
            float p2 = exp2f(s[2][r] - mx), p3 = exp2f(s[3][r] - mx);
            uint2 w;
            w.x = pack2(p0, p1);
            w.y = pack2(p2, p3);
            *(uint2*)&Ps[(wave * 16 + quad * 4 + r) * LDK + 4 * l16] = w;
        }

        // uniform rescale of O and l
        #pragma unroll
        for (int t = 0; t < 4; ++t)
            #pragma unroll
            for (int r = 0; r < 4; ++r)
                o_acc[t][r] *= alpha;
        #pragma unroll
        for (int r = 0; r < 4; ++r) lacc[r] *= alpha;

        // O += P V; l += P . 1 (ones-MFMA)
        #pragma unroll
        for (int ks = 0; ks < 2; ++ks) {
            bf16x8 ap = ld_frag(&Ps[(wave * 16 + l16) * LDK + ks * 32 + quad * 8]);
            #pragma unroll
            for (int t = 0; t < 4; ++t) {
                bf16x8 bv = ld_frag(&Vs[(l16 + 16 * t) * LDK + ks * 32 + quad * 8]);
                o_acc[t] = __builtin_amdgcn_mfma_f32_16x16x32_bf16(ap, bv, o_acc[t], 0, 0, 0);
            }
            lacc = __builtin_amdgcn_mfma_f32_16x16x32_bf16(ap, ones, lacc, 0, 0, 0);
        }
    }

    // store unnormalized partial O (bf16) + (m,l) per row
    const size_t pbase = (size_t)(split * 16 + bh) * N_;
    #pragma unroll
    for (int r = 0; r < 4; ++r) {
        int row = i0 + wave * 16 + quad * 4 + r;
        #pragma unroll
        for (int t = 0; t < 4; ++t)
            Opart[(pbase + row) * D_ + l16 + 16 * t] = f2bf(o_acc[t][r]);
        if (l16 == 0) {
            float2* mlp = (float2*)ml;
            mlp[pbase + row] = make_float2(m_run, lacc[r]);
        }
    }
}

// ---------------- Output projection with fused split-K merge ----------------
// A-staging merges the two attention partials inline; 64x64 tile, 4 waves on M.
__global__ __launch_bounds__(256) void proj_gemm(
    const unsigned short* __restrict__ Opart, const float* __restrict__ ml,
    const unsigned short* __restrict__ wb, const float* __restrict__ bias,
    float* __restrict__ out)
{
    __shared__ __align__(16) unsigned short As[64 * 40];
    __shared__ __align__(16) unsigned short Bs[64 * 40];
    const int m0 = blockIdx.x * 64, o0 = blockIdx.y * 64;
    const int tid = threadIdx.x;
    const int wave = tid >> 6, lane = tid & 63, quad = lane >> 4, l16 = lane & 15;
    const float2* mlp = (const float2*)ml;

    f32x4 acc[4];
    #pragma unroll
    for (int j = 0; j < 4; ++j) acc[j] = (f32x4){0.f, 0.f, 0.f, 0.f};

    for (int k0 = 0; k0 < 256; k0 += 32) {
        __syncthreads();
        {   // A: merge two partials -> bf16 (8 values per thread)
            int row = tid >> 2, cb = (tid & 3) * 8;
            int m = m0 + row;
            int b = m >> 11, n = m & 2047;
            int h = k0 >> 6, d0 = (k0 & 63) + cb;
            size_t r1 = (size_t)(b * 4 + h) * N_ + n;
            size_t r2 = (size_t)(16 + b * 4 + h) * N_ + n;
            float2 ml1 = mlp[r1], ml2 = mlp[r2];
            float mm = fmaxf(ml1.x, ml2.x);
            float w1 = exp2f(ml1.x - mm), w2 = exp2f(ml2.x - mm);
            float inv = 1.f / (ml1.y * w1 + ml2.y * w2);
            w1 *= inv; w2 *= inv;
            union { uint4 u; unsigned short s[8]; } a1, a2;
            a1.u = *(const uint4*)&Opart[r1 * D_ + d0];
            a2.u = *(const uint4*)&Opart[r2 * D_ + d0];
            uint4 mv;
            unsigned* mp = (unsigned*)&mv;
            #pragma unroll
            for (int j = 0; j < 4; ++j)
                mp[j] = pack2(bf2f(a1.s[2*j]) * w1 + bf2f(a2.s[2*j]) * w2,
                              bf2f(a1.s[2*j+1]) * w1 + bf2f(a2.s[2*j+1]) * w2);
            *(uint4*)&As[row * 40 + cb] = mv;
        }
        {   // B: 64x32 bf16 copy
            int row = tid >> 2, cb = (tid & 3) * 8;
            *(uint4*)&Bs[row * 40 + cb] = *(const uint4*)&wb[(size_t)(o0 + row) * 256 + k0 + cb];
        }
        __syncthreads();
        bf16x8 a = ld_frag(&As[(wave * 16 + l16) * 40 + quad * 8]);
        #pragma unroll
        for (int nt = 0; nt < 4; ++nt) {
            bf16x8 b = ld_frag(&Bs[(nt * 16 + l16) * 40 + quad * 8]);
            acc[nt] = __builtin_amdgcn_mfma_f32_16x16x32_bf16(a, b, acc[nt], 0, 0, 0);
        }
    }

    float bv[4];
    #pragma unroll
    for (int nt = 0; nt < 4; ++nt) bv[nt] = bias[o0 + nt * 16 + l16];
    #pragma unroll
    for (int r = 0; r < 4; ++r) {
        int m = m0 + wave * 16 + quad * 4 + r;
        #pragma unroll
        for (int nt = 0; nt < 4; ++nt)
            out[(size_t)m * 256 + o0 + nt * 16 + l16] = acc[nt][r] + bv[nt];
    }
}

extern "C" void kernel_launch(void* const* d_in, const int* in_sizes, int n_in,
                              void* d_out, int out_size, void* d_ws, size_t ws_size,
                              hipStream_t stream) {
    const float* x       = (const float*)d_in[0];
    const float* Rm      = (const float*)d_in[1];
    const float* Pm      = (const float*)d_in[2];
    const float* qkv_w   = (const float*)d_in[3];
    const float* qkv_b   = (const float*)d_in[4];
    const float* proj_w  = (const float*)d_in[5];
    const float* proj_b  = (const float*)d_in[6];
    const float* pos_scl = (const float*)d_in[7];
    float* out = (float*)d_out;

    const size_t NE = (size_t)B_ * H_ * N_ * D_;   // 2,097,152
    unsigned short* xb    = (unsigned short*)d_ws; // 4 MB
    unsigned short* wqb   = xb   + NE;             // 768*256
    unsigned short* wpb   = wqb  + 768 * 256;      // 256*256
    unsigned short* pext  = wpb  + 256 * 256;      // 2048*32
    unsigned short* qb    = pext + 2048 * 32;      // 4 MB each
    unsigned short* kb    = qb   + NE;
    unsigned short* vtb   = kb   + NE;
    unsigned short* opart = vtb  + NE;             // 2*NE = 8 MB
    float*          mlb   = (float*)(opart + 2 * NE);  // 2*16*2048 float2 = 512 KB

    prep_kernel<<<1160, 256, 0, stream>>>(x, qkv_w, proj_w, Pm, xb, wqb, wpb, pext);
    qkv_gemm<<<dim3(64, 12), 256, 0, stream>>>(xb, wqb, qkv_b, qb, kb, vtb);
    attn_kernel<<<dim3(32, 16, 2), 256, 0, stream>>>(qb, kb, vtb, pext, Rm, Pm, pos_scl, opart, mlb);
    proj_gemm<<<dim3(128, 4), 256, 0, stream>>>(opart, mlb, wpb, proj_b, out);
}